// Round 1
// baseline (279.042 us; speedup 1.0000x reference)
//
#include <hip/hip_runtime.h>
#include <hip/hip_bf16.h>

// Problem dims (fixed by reference setup_inputs)
#define B_DIM 4
#define Q_DIM 256
#define D_DIM 256
#define O_DIM 256
#define KTOT 65536L   // D*D
#define SPLIT 32      // K-split factor for big GEMM
#define BM 128
#define BN 128
#define BK 32

typedef __attribute__((ext_vector_type(8))) short short8;
typedef __attribute__((ext_vector_type(4))) float f32x4;
typedef __attribute__((ext_vector_type(4))) unsigned short u16x4;

// RNE float -> bf16 bits (inputs are well-behaved, no NaN handling needed)
static __device__ __forceinline__ unsigned short f2bf(float f) {
    unsigned int u = __builtin_bit_cast(unsigned int, f);
    u += 0x7fffu + ((u >> 16) & 1u);
    return (unsigned short)(u >> 16);
}

// ---------------------------------------------------------------------------
// Kernel 1: T[b,j,k] = (j==k) ? 0 : 1 / (1 - sum_q x[b,q,j]^2 * x[b,q,k]^2)
// grid = B*D blocks (b,j), 256 threads (k)
// ---------------------------------------------------------------------------
__global__ __launch_bounds__(256) void k_compute_T(const float* __restrict__ x,
                                                   float* __restrict__ T) {
    int b = blockIdx.x >> 8;
    int j = blockIdx.x & 255;
    int k = threadIdx.x;
    const float* xb = x + (long)b * Q_DIM * D_DIM;
    float acc = 0.f;
    for (int q = 0; q < Q_DIM; ++q) {
        float xj = xb[(long)q * D_DIM + j];   // uniform across block -> scalar load
        float xk = xb[(long)q * D_DIM + k];   // coalesced
        acc = fmaf(xj * xj, xk * xk, acc);
    }
    float t = (j == k) ? 0.f : 1.f / (1.f - acc);
    T[(long)b * KTOT + (long)j * D_DIM + k] = t;
}

// ---------------------------------------------------------------------------
// Kernel 2: w1T[d][i] = w1[i][d]  (so base-linear reads are coalesced)
// ---------------------------------------------------------------------------
__global__ __launch_bounds__(256) void k_transpose_w1(const float* __restrict__ w1,
                                                      float* __restrict__ w1T) {
    int d = blockIdx.x;
    int i = threadIdx.x;
    w1T[(long)d * O_DIM + i] = w1[(long)i * D_DIM + d];
}

// ---------------------------------------------------------------------------
// Kernel 3: U[m,jk] = bf16( x[m,j] * x[m,k] * T[b,j,k] ), m local to group
// grid = Mg blocks (one per row m), 256 threads; each thread writes 8 bf16/iter
// ---------------------------------------------------------------------------
__global__ __launch_bounds__(256) void k_form_U(const float* __restrict__ x_g,
                                                const float* __restrict__ T_g,
                                                unsigned short* __restrict__ U) {
    int m = blockIdx.x;
    int bl = m >> 8;              // local batch index
    int t = threadIdx.x;
    __shared__ float xs[D_DIM];
    xs[t] = x_g[(long)m * D_DIM + t];
    __syncthreads();
    const float* Tb = T_g + (long)bl * KTOT;
    unsigned short* Ur = U + (long)m * KTOT;
    #pragma unroll 4
    for (int it = 0; it < 32; ++it) {
        int jk = it * 2048 + t * 8;       // 8 consecutive jk, same j (8 | 256)
        int j = jk >> 8;
        int k0 = jk & 255;
        float xj = xs[j];
        f32x4 t0 = *(const f32x4*)(Tb + jk);
        f32x4 t1 = *(const f32x4*)(Tb + jk + 4);
        short8 u;
        u[0] = (short)f2bf(xj * xs[k0 + 0] * t0.x);
        u[1] = (short)f2bf(xj * xs[k0 + 1] * t0.y);
        u[2] = (short)f2bf(xj * xs[k0 + 2] * t0.z);
        u[3] = (short)f2bf(xj * xs[k0 + 3] * t0.w);
        u[4] = (short)f2bf(xj * xs[k0 + 4] * t1.x);
        u[5] = (short)f2bf(xj * xs[k0 + 5] * t1.y);
        u[6] = (short)f2bf(xj * xs[k0 + 6] * t1.z);
        u[7] = (short)f2bf(xj * xs[k0 + 7] * t1.w);
        *(short8*)(Ur + jk) = u;
    }
}

// ---------------------------------------------------------------------------
// Kernel 4: K-split GEMM: partials[sp][m][i] = sum_{k in chunk} U[m,k]*W[i,k]
// A = U (bf16, [Mg][KTOT]), B = lc_w (f32, [256][KTOT]) converted to bf16
// during staging. 128x128 tile, BK=32, 4 waves (2x2), 16x16x32 MFMA, 4x4 frags.
// ---------------------------------------------------------------------------
__global__ __launch_bounds__(256) void k_gemm(const unsigned short* __restrict__ U,
                                              const float* __restrict__ W,
                                              float* __restrict__ partials,
                                              int Mg, int m_tiles) {
    __shared__ unsigned short As[BM][BK];   // 8 KB bf16
    __shared__ unsigned short Bs[BN][BK];   // 8 KB bf16 (converted from f32)

    int bid = blockIdx.x;
    int mt = bid % m_tiles;                 // m-tile fastest: consecutive blocks
    int rest = bid / m_tiles;               //   share the same W chunk (L2/L3)
    int nt = rest & 1;                      // 256/BN = 2
    int sp = rest >> 1;

    int tid = threadIdx.x;
    int lane = tid & 63;
    int wid = tid >> 6;                     // 4 waves
    int wm = wid >> 1, wn = wid & 1;        // 2x2 wave grid, 64x64 each

    const long K = KTOT;
    const long kchunk = K / SPLIT;          // 2048
    const int ksteps = (int)(kchunk / BK);  // 64

    const unsigned short* Ab = U + (long)(mt * BM) * K + (long)sp * kchunk;
    const float* Wb = W + (long)(nt * BN) * K + (long)sp * kchunk;

    f32x4 acc[4][4];
    #pragma unroll
    for (int a = 0; a < 4; ++a)
        #pragma unroll
        for (int b2 = 0; b2 < 4; ++b2)
            acc[a][b2] = (f32x4){0.f, 0.f, 0.f, 0.f};

    int arow = lane >> 2;          // 0..15: row within 16-row stripe
    int acol = (lane & 3) * 8;     // bf16 element offset within row (4x16B=64B)
    int brow = tid >> 3;           // B staging: 32 rows per pass
    int bc4  = (tid & 7) * 4;

    for (int kt = 0; kt < ksteps; ++kt) {
        long kof = (long)kt * BK;
        // --- stage A tile via global_load_lds (wave-uniform dst + lane*16) ---
        #pragma unroll
        for (int r = 0; r < 2; ++r) {
            int rowbase = (r * 4 + wid) * 16;  // 16 rows per issue per wave
            const unsigned short* src = Ab + (long)(rowbase + arow) * K + kof + acol;
            __builtin_amdgcn_global_load_lds(
                (const __attribute__((address_space(1))) unsigned int*)src,
                (__attribute__((address_space(3))) unsigned int*)&As[rowbase][0],
                16, 0, 0);
        }
        // --- stage B tile: f32 load -> bf16 convert -> LDS (4 passes) ---
        #pragma unroll
        for (int p = 0; p < 4; ++p) {
            int row = brow + p * 32;
            f32x4 wv = *(const f32x4*)(Wb + (long)row * K + kof + bc4);
            u16x4 bv;
            bv.x = f2bf(wv.x); bv.y = f2bf(wv.y);
            bv.z = f2bf(wv.z); bv.w = f2bf(wv.w);
            *(u16x4*)&Bs[row][bc4] = bv;
        }
        __syncthreads();   // drains vmcnt (global_load_lds) + lgkm (ds_write)

        short8 af[4], bfr[4];
        #pragma unroll
        for (int mf = 0; mf < 4; ++mf)
            af[mf] = *(const short8*)&As[wm * 64 + mf * 16 + (lane & 15)][(lane >> 4) * 8];
        #pragma unroll
        for (int nf = 0; nf < 4; ++nf)
            bfr[nf] = *(const short8*)&Bs[wn * 64 + nf * 16 + (lane & 15)][(lane >> 4) * 8];
        #pragma unroll
        for (int mf = 0; mf < 4; ++mf)
            #pragma unroll
            for (int nf = 0; nf < 4; ++nf)
                acc[mf][nf] = __builtin_amdgcn_mfma_f32_16x16x32_bf16(af[mf], bfr[nf], acc[mf][nf], 0, 0, 0);
        __syncthreads();   // all waves done reading before next overwrite
    }

    // C/D layout (verified): col = lane&15, row = (lane>>4)*4 + reg
    float* Pp = partials + (long)sp * Mg * O_DIM;
    #pragma unroll
    for (int mf = 0; mf < 4; ++mf) {
        int rowb = mt * BM + wm * 64 + mf * 16 + (lane >> 4) * 4;
        #pragma unroll
        for (int nf = 0; nf < 4; ++nf) {
            int col = nt * BN + wn * 64 + nf * 16 + (lane & 15);
            #pragma unroll
            for (int r = 0; r < 4; ++r)
                Pp[(long)(rowb + r) * O_DIM + col] = acc[mf][nf][r];
        }
    }
}

// ---------------------------------------------------------------------------
// Kernel 5: y[m,i] = bias[i] + sum_sp partials + sum_d x[m,d]*w1T[d,i]
// ---------------------------------------------------------------------------
__global__ __launch_bounds__(256) void k_reduce(const float* __restrict__ partials,
                                                const float* __restrict__ x_g,
                                                const float* __restrict__ w1T,
                                                const float* __restrict__ bias,
                                                float* __restrict__ y_g,
                                                int Mg) {
    int m = blockIdx.x;
    int i = threadIdx.x;
    __shared__ float xs[D_DIM];
    xs[i] = x_g[(long)m * D_DIM + i];
    __syncthreads();
    float acc = bias[i];
    #pragma unroll 4
    for (int s = 0; s < SPLIT; ++s)
        acc += partials[((long)s * Mg + m) * O_DIM + i];
    #pragma unroll 8
    for (int d = 0; d < D_DIM; ++d)
        acc = fmaf(xs[d], w1T[(long)d * O_DIM + i], acc);
    y_g[(long)m * O_DIM + i] = acc;
}

// ---------------------------------------------------------------------------
// Kernel 6: BatchNorm1d over dims (0,2), channel = q. One block per q.
// ---------------------------------------------------------------------------
__global__ __launch_bounds__(256) void k_bn(const float* __restrict__ y,
                                            const float* __restrict__ gamma,
                                            const float* __restrict__ beta,
                                            float* __restrict__ out) {
    int q = blockIdx.x;
    int o = threadIdx.x;
    float v[B_DIM];
    float s = 0.f, s2 = 0.f;
    #pragma unroll
    for (int b = 0; b < B_DIM; ++b) {
        v[b] = y[((long)b * Q_DIM + q) * O_DIM + o];
        s += v[b];
        s2 = fmaf(v[b], v[b], s2);
    }
    #pragma unroll
    for (int off = 32; off > 0; off >>= 1) {
        s  += __shfl_down(s, off, 64);
        s2 += __shfl_down(s2, off, 64);
    }
    __shared__ float rs[4], rq[4];
    int lane = o & 63, wid = o >> 6;
    if (lane == 0) { rs[wid] = s; rq[wid] = s2; }
    __syncthreads();
    float ts = rs[0] + rs[1] + rs[2] + rs[3];
    float tq = rq[0] + rq[1] + rq[2] + rq[3];
    float mean = ts * (1.f / 1024.f);
    float var = tq * (1.f / 1024.f) - mean * mean;   // biased, matches ref
    float rstd = rsqrtf(var + 1e-5f);
    float g = gamma[q], be = beta[q];
    #pragma unroll
    for (int b = 0; b < B_DIM; ++b)
        out[((long)b * Q_DIM + q) * O_DIM + o] = fmaf((v[b] - mean) * rstd, g, be);
}

// ---------------------------------------------------------------------------
extern "C" void kernel_launch(void* const* d_in, const int* in_sizes, int n_in,
                              void* d_out, int out_size, void* d_ws, size_t ws_size,
                              hipStream_t stream) {
    const float* x     = (const float*)d_in[0];
    const float* lc_w  = (const float*)d_in[1];
    const float* w1    = (const float*)d_in[2];
    const float* bias  = (const float*)d_in[3];
    const float* gamma = (const float*)d_in[4];
    const float* beta  = (const float*)d_in[5];
    float* out = (float*)d_out;

    char* ws = (char*)d_ws;
    size_t off = 0;
    auto wsalloc = [&](size_t bytes) {
        size_t o = off;
        off = (off + bytes + 255) & ~(size_t)255;
        return o;
    };
    size_t T_off   = wsalloc((size_t)B_DIM * KTOT * sizeof(float));           // 4 MB
    size_t w1T_off = wsalloc((size_t)D_DIM * O_DIM * sizeof(float));          // 256 KB
    size_t y_off   = wsalloc((size_t)B_DIM * Q_DIM * O_DIM * sizeof(float));  // 1 MB

    // group size: all 4 batches at once if ws allows, else one at a time
    int nb = 4;
    {
        size_t need = off + (size_t)SPLIT * (4 * Q_DIM) * O_DIM * 4
                          + (size_t)(4 * Q_DIM) * KTOT * 2 + 1024;
        if (need > ws_size) nb = 1;
    }
    int Mg = nb * Q_DIM;
    size_t part_off = wsalloc((size_t)SPLIT * Mg * O_DIM * sizeof(float));
    size_t U_off    = wsalloc((size_t)Mg * KTOT * sizeof(unsigned short));

    float* T          = (float*)(ws + T_off);
    float* w1T        = (float*)(ws + w1T_off);
    float* y          = (float*)(ws + y_off);
    float* partials   = (float*)(ws + part_off);
    unsigned short* U = (unsigned short*)(ws + U_off);

    k_compute_T<<<B_DIM * D_DIM, 256, 0, stream>>>(x, T);
    k_transpose_w1<<<D_DIM, 256, 0, stream>>>(w1, w1T);

    int m_tiles = Mg / BM;
    for (int b0 = 0; b0 < B_DIM; b0 += nb) {
        const float* x_g = x + (size_t)b0 * Q_DIM * D_DIM;
        k_form_U<<<Mg, 256, 0, stream>>>(x_g, T + (size_t)b0 * KTOT, U);
        k_gemm<<<m_tiles * 2 * SPLIT, 256, 0, stream>>>(U, lc_w, partials, Mg, m_tiles);
        k_reduce<<<Mg, 256, 0, stream>>>(partials, x_g, w1T, bias,
                                         y + (size_t)b0 * Q_DIM * O_DIM, Mg);
    }
    k_bn<<<Q_DIM, 256, 0, stream>>>(y, gamma, beta, out);
}

// Round 2
// 263.558 us; speedup vs baseline: 1.0588x; 1.0588x over previous
//
#include <hip/hip_runtime.h>
#include <hip/hip_bf16.h>

#define KTOT 65536L

typedef __attribute__((ext_vector_type(8))) short short8;
typedef __attribute__((ext_vector_type(4))) float f32x4;
typedef __attribute__((ext_vector_type(4))) unsigned int u32x4;

static __device__ __forceinline__ unsigned int cvt_pk_bf16(float lo, float hi) {
    unsigned int r;
    asm("v_cvt_pk_bf16_f32 %0, %1, %2" : "=v"(r) : "v"(lo), "v"(hi));
    return r;
}

// ---------------------------------------------------------------------------
// k_pre: T[b,j,k] = (j==k) ? 0 : 1/(1 - sum_q x_j^2 x_k^2)   (4 j-rows/block)
//        + w1T[d][i] = w1[i][d]
// grid = 256 blocks (b = bid>>6, j4 = (bid&63)*4; d = bid), 256 threads
// ---------------------------------------------------------------------------
__global__ __launch_bounds__(256) void k_pre(const float* __restrict__ x,
                                             const float* __restrict__ w1,
                                             float* __restrict__ T,
                                             float* __restrict__ w1T) {
    int bid = blockIdx.x, t = threadIdx.x;
    w1T[(long)bid * 256 + t] = w1[(long)t * 256 + bid];

    int b = bid >> 6;
    int j4 = (bid & 63) * 4;
    const float* xb = x + (long)b * 65536;
    float ac0 = 0.f, ac1 = 0.f, ac2 = 0.f, ac3 = 0.f;
    #pragma unroll 4
    for (int qq = 0; qq < 256; ++qq) {
        const float* row = xb + (long)qq * 256;
        float xk = row[t];
        float xk2 = xk * xk;
        f32x4 aj = *(const f32x4*)(row + j4);
        ac0 = fmaf(aj.x * aj.x, xk2, ac0);
        ac1 = fmaf(aj.y * aj.y, xk2, ac1);
        ac2 = fmaf(aj.z * aj.z, xk2, ac2);
        ac3 = fmaf(aj.w * aj.w, xk2, ac3);
    }
    long base = (long)b * 65536 + (long)j4 * 256 + t;
    T[base +   0] = (j4     == t) ? 0.f : 1.f / (1.f - ac0);
    T[base + 256] = (j4 + 1 == t) ? 0.f : 1.f / (1.f - ac1);
    T[base + 512] = (j4 + 2 == t) ? 0.f : 1.f / (1.f - ac2);
    T[base + 768] = (j4 + 3 == t) ? 0.f : 1.f / (1.f - ac3);
}

// ---------------------------------------------------------------------------
// k_gemm: partials[sp][m][i] = sum_{jk in chunk} (x_j x_k) * (W[i,jk] T[jk])
// A generated in registers from x; B' = bf16(W*T) staged in dbuf LDS.
// 256 blocks (mt = bid>>5, sp = bid&31), 512 threads, BM=128, BN=256, BK=32.
// ---------------------------------------------------------------------------
__global__ __launch_bounds__(512, 2) void k_gemm(const float* __restrict__ x,
                                                 const float* __restrict__ W,
                                                 const float* __restrict__ T,
                                                 float* __restrict__ partials) {
    __shared__ unsigned short Bs[2][256][40];   // +8 bf16 pad: 2-way-conflict reads

    const int bid = blockIdx.x;
    const int mt = bid >> 5;           // 0..7  (m-tile)
    const int sp = bid & 31;           // 0..31 (K-split chunk) — same XCD shares W chunk
    const int tid = threadIdx.x;
    const int lane = tid & 63;
    const int wid = tid >> 6;
    const int wm = wid >> 2;           // 0..1
    const int wn = wid & 3;            // 0..3
    const int c8 = (lane >> 4) * 8;
    const int jbase = sp * 8;
    const int b = mt >> 1;             // batch of this m-tile

    // staging role: 2 threads per W row, 16 f32 each
    const int srow = tid >> 1;
    const int scol = (tid & 1) * 16;
    const float* Wsrc = W + (long)srow * KTOT + (long)jbase * 256 + scol;
    const float* Tsrc = T + (long)b * KTOT + (long)jbase * 256 + scol;

    // A-side registers: xj[mf][jj] (whole kernel), xk (per k-window)
    const float* xr[4];
    float xj[4][8];
    #pragma unroll
    for (int mf = 0; mf < 4; ++mf) {
        int rl = wm * 64 + mf * 16 + (lane & 15);
        xr[mf] = x + (long)(mt * 128 + rl) * 256;
        f32x4 j0 = *(const f32x4*)(xr[mf] + jbase);
        f32x4 j1 = *(const f32x4*)(xr[mf] + jbase + 4);
        xj[mf][0] = j0.x; xj[mf][1] = j0.y; xj[mf][2] = j0.z; xj[mf][3] = j0.w;
        xj[mf][4] = j1.x; xj[mf][5] = j1.y; xj[mf][6] = j1.z; xj[mf][7] = j1.w;
    }

    f32x4 acc[4][4];
    #pragma unroll
    for (int a = 0; a < 4; ++a)
        #pragma unroll
        for (int c = 0; c < 4; ++c) acc[a][c] = (f32x4){0.f, 0.f, 0.f, 0.f};

    // prologue: stage kt=0 (kw=0, jj=0) into Bs[0]
    {
        f32x4 w0 = *(const f32x4*)(Wsrc + 0);
        f32x4 w1v = *(const f32x4*)(Wsrc + 4);
        f32x4 w2 = *(const f32x4*)(Wsrc + 8);
        f32x4 w3 = *(const f32x4*)(Wsrc + 12);
        f32x4 t0 = *(const f32x4*)(Tsrc + 0);
        f32x4 t1 = *(const f32x4*)(Tsrc + 4);
        f32x4 t2 = *(const f32x4*)(Tsrc + 8);
        f32x4 t3 = *(const f32x4*)(Tsrc + 12);
        u32x4 q0, q1;
        q0.x = cvt_pk_bf16(w0.x * t0.x, w0.y * t0.y);
        q0.y = cvt_pk_bf16(w0.z * t0.z, w0.w * t0.w);
        q0.z = cvt_pk_bf16(w1v.x * t1.x, w1v.y * t1.y);
        q0.w = cvt_pk_bf16(w1v.z * t1.z, w1v.w * t1.w);
        q1.x = cvt_pk_bf16(w2.x * t2.x, w2.y * t2.y);
        q1.y = cvt_pk_bf16(w2.z * t2.z, w2.w * t2.w);
        q1.z = cvt_pk_bf16(w3.x * t3.x, w3.y * t3.y);
        q1.w = cvt_pk_bf16(w3.z * t3.z, w3.w * t3.w);
        *(u32x4*)&Bs[0][srow][scol] = q0;
        *(u32x4*)&Bs[0][srow][scol + 8] = q1;
    }
    __syncthreads();

    #pragma unroll 1
    for (int kw = 0; kw < 8; ++kw) {
        // lane-resident xk for this 32-wide k-window (reused across 8 j's)
        f32x4 xk0[4], xk1[4];
        #pragma unroll
        for (int mf = 0; mf < 4; ++mf) {
            xk0[mf] = *(const f32x4*)(xr[mf] + kw * 32 + c8);
            xk1[mf] = *(const f32x4*)(xr[mf] + kw * 32 + c8 + 4);
        }
        #pragma unroll
        for (int jj = 0; jj < 8; ++jj) {
            const int kt = kw * 8 + jj;
            const int buf = kt & 1;
            // 1. issue next-tile W,T loads (kt=63 reads in-bounds garbage, unused)
            const long nof = (long)((kt + 1) >> 3) * 32 + (long)((kt + 1) & 7) * 256;
            f32x4 w0 = *(const f32x4*)(Wsrc + nof);
            f32x4 w1v = *(const f32x4*)(Wsrc + nof + 4);
            f32x4 w2 = *(const f32x4*)(Wsrc + nof + 8);
            f32x4 w3 = *(const f32x4*)(Wsrc + nof + 12);
            f32x4 t0 = *(const f32x4*)(Tsrc + nof);
            f32x4 t1 = *(const f32x4*)(Tsrc + nof + 4);
            f32x4 t2 = *(const f32x4*)(Tsrc + nof + 8);
            f32x4 t3 = *(const f32x4*)(Tsrc + nof + 12);
            // 2. compute kt
            short8 bfv[4];
            #pragma unroll
            for (int nf = 0; nf < 4; ++nf)
                bfv[nf] = *(const short8*)&Bs[buf][wn * 64 + nf * 16 + (lane & 15)][c8];
            short8 afv[4];
            #pragma unroll
            for (int mf = 0; mf < 4; ++mf) {
                const float xje = xj[mf][jj];
                union { unsigned int u[4]; short8 s; } A;
                A.u[0] = cvt_pk_bf16(xje * xk0[mf].x, xje * xk0[mf].y);
                A.u[1] = cvt_pk_bf16(xje * xk0[mf].z, xje * xk0[mf].w);
                A.u[2] = cvt_pk_bf16(xje * xk1[mf].x, xje * xk1[mf].y);
                A.u[3] = cvt_pk_bf16(xje * xk1[mf].z, xje * xk1[mf].w);
                afv[mf] = A.s;
            }
            #pragma unroll
            for (int mf = 0; mf < 4; ++mf)
                #pragma unroll
                for (int nf = 0; nf < 4; ++nf)
                    acc[mf][nf] = __builtin_amdgcn_mfma_f32_16x16x32_bf16(
                        afv[mf], bfv[nf], acc[mf][nf], 0, 0, 0);
            // 3. convert + write next tile into other buffer
            u32x4 q0, q1;
            q0.x = cvt_pk_bf16(w0.x * t0.x, w0.y * t0.y);
            q0.y = cvt_pk_bf16(w0.z * t0.z, w0.w * t0.w);
            q0.z = cvt_pk_bf16(w1v.x * t1.x, w1v.y * t1.y);
            q0.w = cvt_pk_bf16(w1v.z * t1.z, w1v.w * t1.w);
            q1.x = cvt_pk_bf16(w2.x * t2.x, w2.y * t2.y);
            q1.y = cvt_pk_bf16(w2.z * t2.z, w2.w * t2.w);
            q1.z = cvt_pk_bf16(w3.x * t3.x, w3.y * t3.y);
            q1.w = cvt_pk_bf16(w3.z * t3.z, w3.w * t3.w);
            *(u32x4*)&Bs[buf ^ 1][srow][scol] = q0;
            *(u32x4*)&Bs[buf ^ 1][srow][scol + 8] = q1;
            __syncthreads();
        }
    }

    // epilogue: C/D layout col = lane&15, row = (lane>>4)*4 + reg (verified r1)
    float* Pp = partials + (long)sp * 1024 * 256;
    #pragma unroll
    for (int mf = 0; mf < 4; ++mf) {
        int rowb = mt * 128 + wm * 64 + mf * 16 + (lane >> 4) * 4;
        #pragma unroll
        for (int nf = 0; nf < 4; ++nf) {
            int col = wn * 64 + nf * 16 + (lane & 15);
            #pragma unroll
            for (int r = 0; r < 4; ++r)
                Pp[(long)(rowb + r) * 256 + col] = acc[mf][nf][r];
        }
    }
}

// ---------------------------------------------------------------------------
// k_finish: y = sum_sp partials + bias + x@w1T, then BatchNorm over dims (0,2)
// grid = 256 blocks (q), 256 threads (o)
// ---------------------------------------------------------------------------
__global__ __launch_bounds__(256) void k_finish(const float* __restrict__ partials,
                                                const float* __restrict__ x,
                                                const float* __restrict__ w1T,
                                                const float* __restrict__ bias,
                                                const float* __restrict__ gamma,
                                                const float* __restrict__ beta,
                                                float* __restrict__ out) {
    int q = blockIdx.x;
    int o = threadIdx.x;
    __shared__ float xq[256][4];     // [d][b] so base-loop reads one b128 bcast
    #pragma unroll
    for (int bb = 0; bb < 4; ++bb)
        xq[o][bb] = x[((long)bb * 256 + q) * 256 + o];
    __syncthreads();

    float bs = bias[o];
    float a0 = bs, a1 = bs, a2 = bs, a3 = bs;
    // split-K partials
    #pragma unroll 4
    for (int spi = 0; spi < 32; ++spi) {
        const float* P = partials + ((long)spi * 1024 + q) * 256 + o;
        a0 += P[0];
        a1 += P[65536];
        a2 += P[131072];
        a3 += P[196608];
    }
    // base linear
    #pragma unroll 8
    for (int d = 0; d < 256; ++d) {
        float wv = w1T[(long)d * 256 + o];
        f32x4 xv = *(const f32x4*)&xq[d][0];
        a0 = fmaf(xv.x, wv, a0);
        a1 = fmaf(xv.y, wv, a1);
        a2 = fmaf(xv.z, wv, a2);
        a3 = fmaf(xv.w, wv, a3);
    }
    // BatchNorm: stats over the 1024 values of channel q
    float s = a0 + a1 + a2 + a3;
    float sq = a0 * a0 + a1 * a1 + a2 * a2 + a3 * a3;
    #pragma unroll
    for (int off = 32; off > 0; off >>= 1) {
        s  += __shfl_down(s, off, 64);
        sq += __shfl_down(sq, off, 64);
    }
    __shared__ float rs[4], rq[4];
    int lane = o & 63, wv_ = o >> 6;
    if (lane == 0) { rs[wv_] = s; rq[wv_] = sq; }
    __syncthreads();
    float ts = rs[0] + rs[1] + rs[2] + rs[3];
    float tq = rq[0] + rq[1] + rq[2] + rq[3];
    float mean = ts * (1.f / 1024.f);
    float var = tq * (1.f / 1024.f) - mean * mean;   // biased, matches ref
    float rstd = rsqrtf(var + 1e-5f);
    float g = gamma[q], be = beta[q];
    out[((long)0 * 256 + q) * 256 + o] = fmaf((a0 - mean) * rstd, g, be);
    out[((long)1 * 256 + q) * 256 + o] = fmaf((a1 - mean) * rstd, g, be);
    out[((long)2 * 256 + q) * 256 + o] = fmaf((a2 - mean) * rstd, g, be);
    out[((long)3 * 256 + q) * 256 + o] = fmaf((a3 - mean) * rstd, g, be);
}

// ---------------------------------------------------------------------------
extern "C" void kernel_launch(void* const* d_in, const int* in_sizes, int n_in,
                              void* d_out, int out_size, void* d_ws, size_t ws_size,
                              hipStream_t stream) {
    const float* x     = (const float*)d_in[0];
    const float* lc_w  = (const float*)d_in[1];
    const float* w1    = (const float*)d_in[2];
    const float* bias  = (const float*)d_in[3];
    const float* gamma = (const float*)d_in[4];
    const float* beta  = (const float*)d_in[5];
    float* out = (float*)d_out;

    char* ws = (char*)d_ws;
    float* T        = (float*)ws;                                  // 1 MB
    float* w1T      = (float*)(ws + (1 << 20));                    // 256 KB
    float* partials = (float*)(ws + (1 << 20) + (1 << 18));        // 33.55 MB

    k_pre<<<256, 256, 0, stream>>>(x, w1, T, w1T);
    k_gemm<<<256, 512, 0, stream>>>(x, lc_w, T, partials);
    k_finish<<<256, 256, 0, stream>>>(partials, x, w1T, bias, gamma, beta, out);
}

// Round 3
// 242.184 us; speedup vs baseline: 1.1522x; 1.0883x over previous
//
#include <hip/hip_runtime.h>
#include <hip/hip_bf16.h>

typedef __attribute__((ext_vector_type(8))) short short8;
typedef __attribute__((ext_vector_type(4))) float f32x4;
typedef __attribute__((ext_vector_type(4))) unsigned int u32x4;

#define LDP 40   // LDS padded row length in bf16 (80 B: 16B-aligned rows, low conflict)

static __device__ __forceinline__ unsigned int cvt_pk_bf16(float lo, float hi) {
    unsigned int r;
    asm("v_cvt_pk_bf16_f32 %0, %1, %2" : "=v"(r) : "v"(lo), "v"(hi));
    return r;
}

// ---------------------------------------------------------------------------
// k_pre: T[b,j,k] = (j==k) ? 0 : 1/(1 - sum_q x_j^2 x_k^2)   (4 j-rows/block)
//        + w1T[d][i] = w1[i][d]
// ---------------------------------------------------------------------------
__global__ __launch_bounds__(256) void k_pre(const float* __restrict__ x,
                                             const float* __restrict__ w1,
                                             float* __restrict__ T,
                                             float* __restrict__ w1T) {
    int bid = blockIdx.x, t = threadIdx.x;
    w1T[(long)bid * 256 + t] = w1[(long)t * 256 + bid];

    int b = bid >> 6;
    int j4 = (bid & 63) * 4;
    const float* xb = x + (long)b * 65536;
    float ac0 = 0.f, ac1 = 0.f, ac2 = 0.f, ac3 = 0.f;
    #pragma unroll 8
    for (int qq = 0; qq < 256; ++qq) {
        const float* row = xb + (long)qq * 256;
        float xk = row[t];
        float xk2 = xk * xk;
        f32x4 aj = *(const f32x4*)(row + j4);
        ac0 = fmaf(aj.x * aj.x, xk2, ac0);
        ac1 = fmaf(aj.y * aj.y, xk2, ac1);
        ac2 = fmaf(aj.z * aj.z, xk2, ac2);
        ac3 = fmaf(aj.w * aj.w, xk2, ac3);
    }
    long base = (long)b * 65536 + (long)j4 * 256 + t;
    T[base +   0] = (j4     == t) ? 0.f : 1.f / (1.f - ac0);
    T[base + 256] = (j4 + 1 == t) ? 0.f : 1.f / (1.f - ac1);
    T[base + 512] = (j4 + 2 == t) ? 0.f : 1.f / (1.f - ac2);
    T[base + 768] = (j4 + 3 == t) ? 0.f : 1.f / (1.f - ac3);
}

// ---------------------------------------------------------------------------
// k_gemm: partials[sp][m][i] = sum_{jk in chunk} (x_j x_k T[jk]) * W[i,jk]
// m97 structure: 128x128 tile, 4 waves (2x2), BK=32, dbuf LDS both operands.
// A-tile computed into LDS once per block (T folded into A); B = bf16(W).
// grid 512: bid = mt*64 + nt*32 + sp  -> W-chunk & x-tile sharers co-XCD.
// ---------------------------------------------------------------------------
__global__ __launch_bounds__(256, 2) void k_gemm(const float* __restrict__ x,
                                                 const float* __restrict__ W,
                                                 const float* __restrict__ T,
                                                 float* __restrict__ partials) {
    __shared__ unsigned short As[2][128][LDP];   // 20 KB
    __shared__ unsigned short Bs[2][128][LDP];   // 20 KB

    const int bid = blockIdx.x;
    const int mt = bid >> 6;            // 0..7
    const int nt = (bid >> 5) & 1;      // 0..1
    const int sp = bid & 31;            // 0..31
    const int tid = threadIdx.x;
    const int lane = tid & 63;
    const int wid = tid >> 6;
    const int wm = wid >> 1, wn = wid & 1;
    const int b = mt >> 1;              // batch (128 | 256 so tile is batch-pure)

    // staging role: one row, 16 cols per thread
    const int r = tid >> 1;
    const int ch = (tid & 1) * 16;

    const float* xrow = x + (long)(mt * 128 + r) * 256;
    const float* Trow = T + (long)b * 65536 + (long)(sp * 8) * 256 + ch;
    const float* Wrow = W + (long)(nt * 128 + r) * 65536 + (long)(sp * 8) * 256 + ch;

    // x[row][sp*8 .. +7]: the 8 j-values of this chunk (whole-kernel registers)
    f32x4 xjA = *(const f32x4*)(xrow + sp * 8);
    f32x4 xjB = *(const f32x4*)(xrow + sp * 8 + 4);
    const float xj8[8] = {xjA.x, xjA.y, xjA.z, xjA.w, xjB.x, xjB.y, xjB.z, xjB.w};

    f32x4 acc[4][4];
    #pragma unroll
    for (int a = 0; a < 4; ++a)
        #pragma unroll
        for (int c = 0; c < 4; ++c) acc[a][c] = (f32x4){0.f, 0.f, 0.f, 0.f};

    // current x-window registers (k-window of 32, this thread's 16 cols)
    f32x4 xw0, xw1, xw2, xw3;

    // ---- prologue: stage step (kw=0, jj=0) into buf 0 ----
    {
        xw0 = *(const f32x4*)(xrow + ch + 0);
        xw1 = *(const f32x4*)(xrow + ch + 4);
        xw2 = *(const f32x4*)(xrow + ch + 8);
        xw3 = *(const f32x4*)(xrow + ch + 12);
        f32x4 t0 = *(const f32x4*)(Trow + 0);
        f32x4 t1 = *(const f32x4*)(Trow + 4);
        f32x4 t2 = *(const f32x4*)(Trow + 8);
        f32x4 t3 = *(const f32x4*)(Trow + 12);
        f32x4 w0 = *(const f32x4*)(Wrow + 0);
        f32x4 w1 = *(const f32x4*)(Wrow + 4);
        f32x4 w2 = *(const f32x4*)(Wrow + 8);
        f32x4 w3 = *(const f32x4*)(Wrow + 12);
        const float xj = xj8[0];
        u32x4 qa, qb, qc, qd;
        qa.x = cvt_pk_bf16(xj * xw0.x * t0.x, xj * xw0.y * t0.y);
        qa.y = cvt_pk_bf16(xj * xw0.z * t0.z, xj * xw0.w * t0.w);
        qa.z = cvt_pk_bf16(xj * xw1.x * t1.x, xj * xw1.y * t1.y);
        qa.w = cvt_pk_bf16(xj * xw1.z * t1.z, xj * xw1.w * t1.w);
        qb.x = cvt_pk_bf16(xj * xw2.x * t2.x, xj * xw2.y * t2.y);
        qb.y = cvt_pk_bf16(xj * xw2.z * t2.z, xj * xw2.w * t2.w);
        qb.z = cvt_pk_bf16(xj * xw3.x * t3.x, xj * xw3.y * t3.y);
        qb.w = cvt_pk_bf16(xj * xw3.z * t3.z, xj * xw3.w * t3.w);
        qc.x = cvt_pk_bf16(w0.x, w0.y);  qc.y = cvt_pk_bf16(w0.z, w0.w);
        qc.z = cvt_pk_bf16(w1.x, w1.y);  qc.w = cvt_pk_bf16(w1.z, w1.w);
        qd.x = cvt_pk_bf16(w2.x, w2.y);  qd.y = cvt_pk_bf16(w2.z, w2.w);
        qd.z = cvt_pk_bf16(w3.x, w3.y);  qd.w = cvt_pk_bf16(w3.z, w3.w);
        *(u32x4*)&As[0][r][ch]     = qa;
        *(u32x4*)&As[0][r][ch + 8] = qb;
        *(u32x4*)&Bs[0][r][ch]     = qc;
        *(u32x4*)&Bs[0][r][ch + 8] = qd;
    }
    __syncthreads();

    #pragma unroll 1
    for (int kw = 0; kw < 8; ++kw) {
        #pragma unroll
        for (int jj = 0; jj < 8; ++jj) {
            const int buf = jj & 1;            // (kw*8+jj)&1 == jj&1
            const int njj = (jj + 1) & 7;
            const int nkw = (jj == 7) ? kw + 1 : kw;
            // ---- 1. issue next-step loads (consumed after the MFMAs) ----
            const long noff = (long)njj * 256 + (long)nkw * 32;
            f32x4 t0 = *(const f32x4*)(Trow + noff + 0);
            f32x4 t1 = *(const f32x4*)(Trow + noff + 4);
            f32x4 t2 = *(const f32x4*)(Trow + noff + 8);
            f32x4 t3 = *(const f32x4*)(Trow + noff + 12);
            f32x4 w0 = *(const f32x4*)(Wrow + noff + 0);
            f32x4 w1 = *(const f32x4*)(Wrow + noff + 4);
            f32x4 w2 = *(const f32x4*)(Wrow + noff + 8);
            f32x4 w3 = *(const f32x4*)(Wrow + noff + 12);
            f32x4 nx0, nx1, nx2, nx3;
            if (jj == 7) {   // new k-window next step (clamp last: garbage unused)
                const long xo = (kw == 7) ? 0 : (long)(kw + 1) * 32;
                nx0 = *(const f32x4*)(xrow + xo + ch + 0);
                nx1 = *(const f32x4*)(xrow + xo + ch + 4);
                nx2 = *(const f32x4*)(xrow + xo + ch + 8);
                nx3 = *(const f32x4*)(xrow + xo + ch + 12);
            } else { nx0 = xw0; nx1 = xw1; nx2 = xw2; nx3 = xw3; }

            // ---- 2. fragments + MFMA from buf ----
            short8 af[4], bfv[4];
            #pragma unroll
            for (int mf = 0; mf < 4; ++mf)
                af[mf] = *(const short8*)&As[buf][wm * 64 + mf * 16 + (lane & 15)][(lane >> 4) * 8];
            #pragma unroll
            for (int nf = 0; nf < 4; ++nf)
                bfv[nf] = *(const short8*)&Bs[buf][wn * 64 + nf * 16 + (lane & 15)][(lane >> 4) * 8];
            #pragma unroll
            for (int mf = 0; mf < 4; ++mf)
                #pragma unroll
                for (int nf = 0; nf < 4; ++nf)
                    acc[mf][nf] = __builtin_amdgcn_mfma_f32_16x16x32_bf16(
                        af[mf], bfv[nf], acc[mf][nf], 0, 0, 0);

            // ---- 3. convert + stage next step into buf^1 ----
            const float xjn = xj8[njj];
            u32x4 qa, qb, qc, qd;
            qa.x = cvt_pk_bf16(xjn * nx0.x * t0.x, xjn * nx0.y * t0.y);
            qa.y = cvt_pk_bf16(xjn * nx0.z * t0.z, xjn * nx0.w * t0.w);
            qa.z = cvt_pk_bf16(xjn * nx1.x * t1.x, xjn * nx1.y * t1.y);
            qa.w = cvt_pk_bf16(xjn * nx1.z * t1.z, xjn * nx1.w * t1.w);
            qb.x = cvt_pk_bf16(xjn * nx2.x * t2.x, xjn * nx2.y * t2.y);
            qb.y = cvt_pk_bf16(xjn * nx2.z * t2.z, xjn * nx2.w * t2.w);
            qb.z = cvt_pk_bf16(xjn * nx3.x * t3.x, xjn * nx3.y * t3.y);
            qb.w = cvt_pk_bf16(xjn * nx3.z * t3.z, xjn * nx3.w * t3.w);
            qc.x = cvt_pk_bf16(w0.x, w0.y);  qc.y = cvt_pk_bf16(w0.z, w0.w);
            qc.z = cvt_pk_bf16(w1.x, w1.y);  qc.w = cvt_pk_bf16(w1.z, w1.w);
            qd.x = cvt_pk_bf16(w2.x, w2.y);  qd.y = cvt_pk_bf16(w2.z, w2.w);
            qd.z = cvt_pk_bf16(w3.x, w3.y);  qd.w = cvt_pk_bf16(w3.z, w3.w);
            *(u32x4*)&As[buf ^ 1][r][ch]     = qa;
            *(u32x4*)&As[buf ^ 1][r][ch + 8] = qb;
            *(u32x4*)&Bs[buf ^ 1][r][ch]     = qc;
            *(u32x4*)&Bs[buf ^ 1][r][ch + 8] = qd;
            __syncthreads();
            if (jj == 7) { xw0 = nx0; xw1 = nx1; xw2 = nx2; xw3 = nx3; }
        }
    }

    // epilogue: C/D layout col = lane&15, row = (lane>>4)*4 + reg (verified r1/r2)
    float* Pp = partials + (long)sp * 1024 * 256;
    #pragma unroll
    for (int mf = 0; mf < 4; ++mf) {
        int rowb = mt * 128 + wm * 64 + mf * 16 + (lane >> 4) * 4;
        #pragma unroll
        for (int nf = 0; nf < 4; ++nf) {
            int col = nt * 128 + wn * 64 + nf * 16 + (lane & 15);
            #pragma unroll
            for (int rr = 0; rr < 4; ++rr)
                Pp[(long)(rowb + rr) * 256 + col] = acc[mf][nf][rr];
        }
    }
}

// ---------------------------------------------------------------------------
// k_sum: y[m,o] = bias[o] + sum_sp partials[sp][m][o] + sum_d x[m,d] w1T[d,o]
//        + per-row (m) stats: bstats[m] = (sum_o y, sum_o y^2)
// grid = 1024 blocks (m), 256 threads (o)
// ---------------------------------------------------------------------------
__global__ __launch_bounds__(256) void k_sum(const float* __restrict__ partials,
                                             const float* __restrict__ x,
                                             const float* __restrict__ w1T,
                                             const float* __restrict__ bias,
                                             float* __restrict__ y,
                                             float2* __restrict__ bstats) {
    int m = blockIdx.x;
    int o = threadIdx.x;
    __shared__ float xs[256];
    xs[o] = x[(long)m * 256 + o];
    __syncthreads();

    float acc = bias[o];
    #pragma unroll 8
    for (int spi = 0; spi < 32; ++spi)
        acc += partials[((long)spi * 1024 + m) * 256 + o];
    #pragma unroll 8
    for (int d = 0; d < 256; ++d)
        acc = fmaf(xs[d], w1T[(long)d * 256 + o], acc);
    y[(long)m * 256 + o] = acc;

    float s = acc, s2 = acc * acc;
    #pragma unroll
    for (int off = 32; off > 0; off >>= 1) {
        s  += __shfl_down(s, off, 64);
        s2 += __shfl_down(s2, off, 64);
    }
    __shared__ float rs[4], rq[4];
    int lane = o & 63, wv = o >> 6;
    if (lane == 0) { rs[wv] = s; rq[wv] = s2; }
    __syncthreads();
    if (o == 0) {
        float2 st;
        st.x = rs[0] + rs[1] + rs[2] + rs[3];
        st.y = rq[0] + rq[1] + rq[2] + rq[3];
        bstats[m] = st;
    }
}

// ---------------------------------------------------------------------------
// k_bn: per channel q (= m&255): stats over the 4 b-rows, normalize, write out
// grid = 1024 blocks (m), 256 threads (o)
// ---------------------------------------------------------------------------
__global__ __launch_bounds__(256) void k_bn(const float* __restrict__ y,
                                            const float2* __restrict__ bstats,
                                            const float* __restrict__ gamma,
                                            const float* __restrict__ beta,
                                            float* __restrict__ out) {
    int m = blockIdx.x;
    int o = threadIdx.x;
    int q = m & 255;
    float2 s0 = bstats[q], s1 = bstats[256 + q], s2 = bstats[512 + q], s3 = bstats[768 + q];
    float ts = s0.x + s1.x + s2.x + s3.x;
    float tq = s0.y + s1.y + s2.y + s3.y;
    float mean = ts * (1.f / 1024.f);
    float var = tq * (1.f / 1024.f) - mean * mean;   // biased, matches ref
    float rstd = rsqrtf(var + 1e-5f);
    float v = y[(long)m * 256 + o];
    out[(long)m * 256 + o] = fmaf((v - mean) * rstd, gamma[q], beta[q]);
}

// ---------------------------------------------------------------------------
extern "C" void kernel_launch(void* const* d_in, const int* in_sizes, int n_in,
                              void* d_out, int out_size, void* d_ws, size_t ws_size,
                              hipStream_t stream) {
    const float* x     = (const float*)d_in[0];
    const float* lc_w  = (const float*)d_in[1];
    const float* w1    = (const float*)d_in[2];
    const float* bias  = (const float*)d_in[3];
    const float* gamma = (const float*)d_in[4];
    const float* beta  = (const float*)d_in[5];
    float* out = (float*)d_out;

    char* ws = (char*)d_ws;
    float*  T        = (float*)ws;                                      // 1 MB
    float*  w1T      = (float*)(ws + (1u << 20));                       // 256 KB
    float*  partials = (float*)(ws + (1u << 20) + (1u << 18));          // 33.55 MB
    char*   after_p  = ws + (1u << 20) + (1u << 18) + ((size_t)32 * 1024 * 256 * 4);
    float*  y        = (float*)after_p;                                 // 1 MB
    float2* bstats   = (float2*)(after_p + (1u << 20));                 // 8 KB

    k_pre <<<256,  256, 0, stream>>>(x, w1, T, w1T);
    k_gemm<<<512,  256, 0, stream>>>(x, lc_w, T, partials);
    k_sum <<<1024, 256, 0, stream>>>(partials, x, w1T, bias, y, bstats);
    k_bn  <<<1024, 256, 0, stream>>>(y, bstats, gamma, beta, out);
}

// Round 4
// 205.807 us; speedup vs baseline: 1.3558x; 1.1768x over previous
//
#include <hip/hip_runtime.h>
#include <hip/hip_bf16.h>

typedef __attribute__((ext_vector_type(8))) short short8;
typedef __attribute__((ext_vector_type(4))) float f32x4;
typedef __attribute__((ext_vector_type(4))) unsigned int u32x4;

#define LDP 40   // padded A rows (80 B) — low-conflict ds_write/ds_read

static __device__ __forceinline__ unsigned int cvt_pk_bf16(float lo, float hi) {
    unsigned int r;
    asm("v_cvt_pk_bf16_f32 %0, %1, %2" : "=v"(r) : "v"(lo), "v"(hi));
    return r;
}

// ---------------------------------------------------------------------------
// k_wcvt: Wbf = bf16(lc_w)  [256][65536], w1bf = bf16(w1) [256][256]
// coalesced streaming convert (the GEMM then loads W with 64B-row segments)
// ---------------------------------------------------------------------------
__global__ __launch_bounds__(256) void k_wcvt(const float* __restrict__ W,
                                              const float* __restrict__ w1,
                                              unsigned short* __restrict__ Wbf,
                                              unsigned short* __restrict__ w1bf) {
    long g = (long)blockIdx.x * 256 + threadIdx.x;
    long stride = (long)gridDim.x * 256;
    for (long i = g * 8; i < 16777216L; i += stride * 8) {
        f32x4 a = *(const f32x4*)(W + i);
        f32x4 b = *(const f32x4*)(W + i + 4);
        u32x4 q;
        q.x = cvt_pk_bf16(a.x, a.y); q.y = cvt_pk_bf16(a.z, a.w);
        q.z = cvt_pk_bf16(b.x, b.y); q.w = cvt_pk_bf16(b.z, b.w);
        *(u32x4*)(Wbf + i) = q;
    }
    for (long i = g * 8; i < 65536L; i += stride * 8) {
        f32x4 a = *(const f32x4*)(w1 + i);
        f32x4 b = *(const f32x4*)(w1 + i + 4);
        u32x4 q;
        q.x = cvt_pk_bf16(a.x, a.y); q.y = cvt_pk_bf16(a.z, a.w);
        q.z = cvt_pk_bf16(b.x, b.y); q.w = cvt_pk_bf16(b.z, b.w);
        *(u32x4*)(w1bf + i) = q;
    }
}

// ---------------------------------------------------------------------------
// k_pre: T[b,j,k] = (j==k) ? 0 : 1/(1 - sum_q x_j^2 x_k^2)   (4 j-rows/block)
// ---------------------------------------------------------------------------
__global__ __launch_bounds__(256) void k_pre(const float* __restrict__ x,
                                             float* __restrict__ T) {
    int bid = blockIdx.x, t = threadIdx.x;
    int b = bid >> 6;
    int j4 = (bid & 63) * 4;
    const float* xb = x + (long)b * 65536;
    float ac0 = 0.f, ac1 = 0.f, ac2 = 0.f, ac3 = 0.f;
    #pragma unroll 8
    for (int qq = 0; qq < 256; ++qq) {
        const float* row = xb + (long)qq * 256;
        float xk = row[t];
        float xk2 = xk * xk;
        f32x4 aj = *(const f32x4*)(row + j4);
        ac0 = fmaf(aj.x * aj.x, xk2, ac0);
        ac1 = fmaf(aj.y * aj.y, xk2, ac1);
        ac2 = fmaf(aj.z * aj.z, xk2, ac2);
        ac3 = fmaf(aj.w * aj.w, xk2, ac3);
    }
    long base = (long)b * 65536 + (long)j4 * 256 + t;
    T[base +   0] = (j4     == t) ? 0.f : 1.f / (1.f - ac0);
    T[base + 256] = (j4 + 1 == t) ? 0.f : 1.f / (1.f - ac1);
    T[base + 512] = (j4 + 2 == t) ? 0.f : 1.f / (1.f - ac2);
    T[base + 768] = (j4 + 3 == t) ? 0.f : 1.f / (1.f - ac3);
}

// ---------------------------------------------------------------------------
// k_gemm: partials[sp][m][i] = sum_{jk chunk} (x_j x_k T[jk]) * W[i,jk]
//   B = bf16 W via global_load_lds (16 lines/instr, coalesced) into linear LDS
//   A = computed in-register from x,T (broadcast/cheap loads), padded LDS
//   sp<8 blocks append one K-step of the base linear (A=bf16(x), B=w1bf)
// grid 512: bid = mt*64 + nt*32 + sp  (W-chunk sharers land on one XCD)
// ---------------------------------------------------------------------------
__global__ __launch_bounds__(256, 3) void k_gemm(const float* __restrict__ x,
                                                 const unsigned short* __restrict__ Wbf,
                                                 const unsigned short* __restrict__ w1bf,
                                                 const float* __restrict__ T,
                                                 float* __restrict__ partials) {
    __shared__ unsigned short As[2][128][LDP];   // 20 KB
    __shared__ unsigned short Bs[2][128][32];    // 16 KB, linear for global_load_lds

    const int bid = blockIdx.x;
    const int mt = bid >> 6;            // 0..7
    const int nt = (bid >> 5) & 1;      // 0..1
    const int sp = bid & 31;            // 0..31
    const int tid = threadIdx.x;
    const int lane = tid & 63;
    const int wid = tid >> 6;
    const int wm = wid >> 1, wn = wid & 1;
    const int b = mt >> 1;

    // A staging role: one row, 16 cols per thread
    const int r = tid >> 1;
    const int ch = (tid & 1) * 16;

    const float* xrow = x + (long)(mt * 128 + r) * 256;
    const float* Trow = T + (long)b * 65536 + (long)(sp * 8) * 256 + ch;

    // B staging: wave wid covers rows wid*32..+32 (2 gload_lds, 16 rows each)
    const long browg = (long)(nt * 128 + wid * 32 + (lane >> 2));
    const unsigned short* Bsrc0 = Wbf + browg * 65536 + (long)sp * 2048 + (lane & 3) * 8;
    const unsigned short* Bsrc1 = Bsrc0 + 16L * 65536;

    // the 8 j-values of this chunk for this thread's A row
    f32x4 xjA = *(const f32x4*)(xrow + sp * 8);
    f32x4 xjB = *(const f32x4*)(xrow + sp * 8 + 4);
    const float xj8[8] = {xjA.x, xjA.y, xjA.z, xjA.w, xjB.x, xjB.y, xjB.z, xjB.w};

    f32x4 acc[4][4];
    #pragma unroll
    for (int a = 0; a < 4; ++a)
        #pragma unroll
        for (int c = 0; c < 4; ++c) acc[a][c] = (f32x4){0.f, 0.f, 0.f, 0.f};

    f32x4 xw0, xw1, xw2, xw3;   // current k-window x (this thread's 16 cols)

    // ---- prologue: stage step 0 into buf 0 ----
    {
        __builtin_amdgcn_global_load_lds(
            (const __attribute__((address_space(1))) unsigned int*)Bsrc0,
            (__attribute__((address_space(3))) unsigned int*)&Bs[0][wid * 32][0], 16, 0, 0);
        __builtin_amdgcn_global_load_lds(
            (const __attribute__((address_space(1))) unsigned int*)Bsrc1,
            (__attribute__((address_space(3))) unsigned int*)&Bs[0][wid * 32 + 16][0], 16, 0, 0);
        xw0 = *(const f32x4*)(xrow + ch + 0);
        xw1 = *(const f32x4*)(xrow + ch + 4);
        xw2 = *(const f32x4*)(xrow + ch + 8);
        xw3 = *(const f32x4*)(xrow + ch + 12);
        f32x4 t0 = *(const f32x4*)(Trow + 0);
        f32x4 t1 = *(const f32x4*)(Trow + 4);
        f32x4 t2 = *(const f32x4*)(Trow + 8);
        f32x4 t3 = *(const f32x4*)(Trow + 12);
        const float xj = xj8[0];
        u32x4 qa, qb;
        qa.x = cvt_pk_bf16(xj * xw0.x * t0.x, xj * xw0.y * t0.y);
        qa.y = cvt_pk_bf16(xj * xw0.z * t0.z, xj * xw0.w * t0.w);
        qa.z = cvt_pk_bf16(xj * xw1.x * t1.x, xj * xw1.y * t1.y);
        qa.w = cvt_pk_bf16(xj * xw1.z * t1.z, xj * xw1.w * t1.w);
        qb.x = cvt_pk_bf16(xj * xw2.x * t2.x, xj * xw2.y * t2.y);
        qb.y = cvt_pk_bf16(xj * xw2.z * t2.z, xj * xw2.w * t2.w);
        qb.z = cvt_pk_bf16(xj * xw3.x * t3.x, xj * xw3.y * t3.y);
        qb.w = cvt_pk_bf16(xj * xw3.z * t3.z, xj * xw3.w * t3.w);
        *(u32x4*)&As[0][r][ch]     = qa;
        *(u32x4*)&As[0][r][ch + 8] = qb;
    }
    __syncthreads();

    #pragma unroll 1
    for (int kw = 0; kw < 8; ++kw) {
        #pragma unroll
        for (int jj = 0; jj < 8; ++jj) {
            const int buf = jj & 1;
            const int nbuf = buf ^ 1;
            const int njj = (jj + 1) & 7;
            const int nkw = (jj == 7) ? kw + 1 : kw;
            const bool last = (jj == 7) && (kw == 7);

            // ---- 1. issue next-step B (gload_lds) + T/x loads ----
            f32x4 t0, t1, t2, t3;
            f32x4 nx0 = xw0, nx1 = xw1, nx2 = xw2, nx3 = xw3;
            if (!last) {
                const long noff = (long)njj * 256 + (long)nkw * 32;   // bf16 elems
                __builtin_amdgcn_global_load_lds(
                    (const __attribute__((address_space(1))) unsigned int*)(Bsrc0 + noff),
                    (__attribute__((address_space(3))) unsigned int*)&Bs[nbuf][wid * 32][0], 16, 0, 0);
                __builtin_amdgcn_global_load_lds(
                    (const __attribute__((address_space(1))) unsigned int*)(Bsrc1 + noff),
                    (__attribute__((address_space(3))) unsigned int*)&Bs[nbuf][wid * 32 + 16][0], 16, 0, 0);
                t0 = *(const f32x4*)(Trow + noff + 0);
                t1 = *(const f32x4*)(Trow + noff + 4);
                t2 = *(const f32x4*)(Trow + noff + 8);
                t3 = *(const f32x4*)(Trow + noff + 12);
                if (jj == 7) {
                    const long xo = (long)(kw + 1) * 32;
                    nx0 = *(const f32x4*)(xrow + xo + ch + 0);
                    nx1 = *(const f32x4*)(xrow + xo + ch + 4);
                    nx2 = *(const f32x4*)(xrow + xo + ch + 8);
                    nx3 = *(const f32x4*)(xrow + xo + ch + 12);
                }
            }

            // ---- 2. fragments + 16 MFMA from buf ----
            short8 af[4], bfv[4];
            #pragma unroll
            for (int mf = 0; mf < 4; ++mf)
                af[mf] = *(const short8*)&As[buf][wm * 64 + mf * 16 + (lane & 15)][(lane >> 4) * 8];
            #pragma unroll
            for (int nf = 0; nf < 4; ++nf)
                bfv[nf] = *(const short8*)&Bs[buf][wn * 64 + nf * 16 + (lane & 15)][(lane >> 4) * 8];
            #pragma unroll
            for (int mf = 0; mf < 4; ++mf)
                #pragma unroll
                for (int nf = 0; nf < 4; ++nf)
                    acc[mf][nf] = __builtin_amdgcn_mfma_f32_16x16x32_bf16(
                        af[mf], bfv[nf], acc[mf][nf], 0, 0, 0);

            // ---- 3. compute + write next A tile ----
            if (!last) {
                const float xjn = xj8[njj];
                u32x4 qa, qb;
                qa.x = cvt_pk_bf16(xjn * nx0.x * t0.x, xjn * nx0.y * t0.y);
                qa.y = cvt_pk_bf16(xjn * nx0.z * t0.z, xjn * nx0.w * t0.w);
                qa.z = cvt_pk_bf16(xjn * nx1.x * t1.x, xjn * nx1.y * t1.y);
                qa.w = cvt_pk_bf16(xjn * nx1.z * t1.z, xjn * nx1.w * t1.w);
                qb.x = cvt_pk_bf16(xjn * nx2.x * t2.x, xjn * nx2.y * t2.y);
                qb.y = cvt_pk_bf16(xjn * nx2.z * t2.z, xjn * nx2.w * t2.w);
                qb.z = cvt_pk_bf16(xjn * nx3.x * t3.x, xjn * nx3.y * t3.y);
                qb.w = cvt_pk_bf16(xjn * nx3.z * t3.z, xjn * nx3.w * t3.w);
                *(u32x4*)&As[nbuf][r][ch]     = qa;
                *(u32x4*)&As[nbuf][r][ch + 8] = qb;
            }
            __syncthreads();
            if (jj == 7) { xw0 = nx0; xw1 = nx1; xw2 = nx2; xw3 = nx3; }
        }
    }

    // ---- base-linear fold: sp<8 blocks do one extra K-step over w1 ----
    if (sp < 8) {
        const unsigned short* W1s = w1bf + (long)(nt * 128 + wid * 32 + (lane >> 2)) * 256
                                        + sp * 32 + (lane & 3) * 8;
        __builtin_amdgcn_global_load_lds(
            (const __attribute__((address_space(1))) unsigned int*)W1s,
            (__attribute__((address_space(3))) unsigned int*)&Bs[0][wid * 32][0], 16, 0, 0);
        __builtin_amdgcn_global_load_lds(
            (const __attribute__((address_space(1))) unsigned int*)(W1s + 16L * 256),
            (__attribute__((address_space(3))) unsigned int*)&Bs[0][wid * 32 + 16][0], 16, 0, 0);
        f32x4 a0 = *(const f32x4*)(xrow + sp * 32 + ch + 0);
        f32x4 a1 = *(const f32x4*)(xrow + sp * 32 + ch + 4);
        f32x4 a2 = *(const f32x4*)(xrow + sp * 32 + ch + 8);
        f32x4 a3 = *(const f32x4*)(xrow + sp * 32 + ch + 12);
        u32x4 qa, qb;
        qa.x = cvt_pk_bf16(a0.x, a0.y); qa.y = cvt_pk_bf16(a0.z, a0.w);
        qa.z = cvt_pk_bf16(a1.x, a1.y); qa.w = cvt_pk_bf16(a1.z, a1.w);
        qb.x = cvt_pk_bf16(a2.x, a2.y); qb.y = cvt_pk_bf16(a2.z, a2.w);
        qb.z = cvt_pk_bf16(a3.x, a3.y); qb.w = cvt_pk_bf16(a3.z, a3.w);
        *(u32x4*)&As[0][r][ch]     = qa;
        *(u32x4*)&As[0][r][ch + 8] = qb;
        __syncthreads();
        short8 af[4], bfv[4];
        #pragma unroll
        for (int mf = 0; mf < 4; ++mf)
            af[mf] = *(const short8*)&As[0][wm * 64 + mf * 16 + (lane & 15)][(lane >> 4) * 8];
        #pragma unroll
        for (int nf = 0; nf < 4; ++nf)
            bfv[nf] = *(const short8*)&Bs[0][wn * 64 + nf * 16 + (lane & 15)][(lane >> 4) * 8];
        #pragma unroll
        for (int mf = 0; mf < 4; ++mf)
            #pragma unroll
            for (int nf = 0; nf < 4; ++nf)
                acc[mf][nf] = __builtin_amdgcn_mfma_f32_16x16x32_bf16(
                    af[mf], bfv[nf], acc[mf][nf], 0, 0, 0);
    }

    // epilogue: C/D layout col = lane&15, row = (lane>>4)*4 + reg
    float* Pp = partials + (long)sp * 1024 * 256;
    #pragma unroll
    for (int mf = 0; mf < 4; ++mf) {
        int rowb = mt * 128 + wm * 64 + mf * 16 + (lane >> 4) * 4;
        #pragma unroll
        for (int nf = 0; nf < 4; ++nf) {
            int col = nt * 128 + wn * 64 + nf * 16 + (lane & 15);
            #pragma unroll
            for (int rr = 0; rr < 4; ++rr)
                Pp[(long)(rowb + rr) * 256 + col] = acc[mf][nf][rr];
        }
    }
}

// ---------------------------------------------------------------------------
// k_sum: y[m,o] = bias[o] + sum_sp partials[sp][m][o]; per-row stats
// ---------------------------------------------------------------------------
__global__ __launch_bounds__(256) void k_sum(const float* __restrict__ partials,
                                             const float* __restrict__ bias,
                                             float* __restrict__ y,
                                             float2* __restrict__ bstats) {
    int m = blockIdx.x;
    int o = threadIdx.x;
    float acc = bias[o];
    #pragma unroll 8
    for (int spi = 0; spi < 32; ++spi)
        acc += partials[((long)spi * 1024 + m) * 256 + o];
    y[(long)m * 256 + o] = acc;

    float s = acc, s2 = acc * acc;
    #pragma unroll
    for (int off = 32; off > 0; off >>= 1) {
        s  += __shfl_down(s, off, 64);
        s2 += __shfl_down(s2, off, 64);
    }
    __shared__ float rs[4], rq[4];
    int lane = o & 63, wv = o >> 6;
    if (lane == 0) { rs[wv] = s; rq[wv] = s2; }
    __syncthreads();
    if (o == 0) {
        float2 st;
        st.x = rs[0] + rs[1] + rs[2] + rs[3];
        st.y = rq[0] + rq[1] + rq[2] + rq[3];
        bstats[m] = st;
    }
}

// ---------------------------------------------------------------------------
// k_bn: channel q = m&255: combine 4 b-row stats, normalize, write out
// ---------------------------------------------------------------------------
__global__ __launch_bounds__(256) void k_bn(const float* __restrict__ y,
                                            const float2* __restrict__ bstats,
                                            const float* __restrict__ gamma,
                                            const float* __restrict__ beta,
                                            float* __restrict__ out) {
    int m = blockIdx.x;
    int o = threadIdx.x;
    int q = m & 255;
    float2 s0 = bstats[q], s1 = bstats[256 + q], s2 = bstats[512 + q], s3 = bstats[768 + q];
    float ts = s0.x + s1.x + s2.x + s3.x;
    float tq = s0.y + s1.y + s2.y + s3.y;
    float mean = ts * (1.f / 1024.f);
    float var = tq * (1.f / 1024.f) - mean * mean;   // biased, matches ref
    float rstd = rsqrtf(var + 1e-5f);
    float v = y[(long)m * 256 + o];
    out[(long)m * 256 + o] = fmaf((v - mean) * rstd, gamma[q], beta[q]);
}

// ---------------------------------------------------------------------------
extern "C" void kernel_launch(void* const* d_in, const int* in_sizes, int n_in,
                              void* d_out, int out_size, void* d_ws, size_t ws_size,
                              hipStream_t stream) {
    const float* x     = (const float*)d_in[0];
    const float* lc_w  = (const float*)d_in[1];
    const float* w1    = (const float*)d_in[2];
    const float* bias  = (const float*)d_in[3];
    const float* gamma = (const float*)d_in[4];
    const float* beta  = (const float*)d_in[5];
    float* out = (float*)d_out;

    char* ws = (char*)d_ws;
    size_t o_T     = 0;                       // 1 MB
    size_t o_part  = o_T + 1048576;           // 33.55 MB
    size_t o_y     = o_part + 33554432;       // 1 MB
    size_t o_bst   = o_y + 1048576;           // 8 KB
    size_t o_Wbf   = o_bst + 8192;            // 32 MB
    size_t o_w1bf  = o_Wbf + 33554432;        // 128 KB

    float*          T        = (float*)(ws + o_T);
    float*          partials = (float*)(ws + o_part);
    float*          y        = (float*)(ws + o_y);
    float2*         bstats   = (float2*)(ws + o_bst);
    unsigned short* Wbf      = (unsigned short*)(ws + o_Wbf);
    unsigned short* w1bf     = (unsigned short*)(ws + o_w1bf);

    k_wcvt<<<2048, 256, 0, stream>>>(lc_w, w1, Wbf, w1bf);
    k_pre <<<256,  256, 0, stream>>>(x, T);
    k_gemm<<<512,  256, 0, stream>>>(x, Wbf, w1bf, T, partials);
    k_sum <<<1024, 256, 0, stream>>>(partials, bias, y, bstats);
    k_bn  <<<1024, 256, 0, stream>>>(y, bstats, gamma, beta, out);
}